// Round 6
// baseline (257.543 us; speedup 1.0000x reference)
//
#include <hip/hip_runtime.h>

#define EPS 1e-5f

#define B    512
#define C_IN 12
#define L_IN 5000
#define C1   32
#define L1   496   // (5000-50)/10+1
#define NF   32
#define L2   95    // (496-25)/5+1
#define LAT  32
#define HID  64
#define T    L2

typedef short s16x8 __attribute__((ext_vector_type(8)));
typedef float f32x16 __attribute__((ext_vector_type(16)));

__device__ __forceinline__ ushort f2bf(float f) {   // RNE float->bf16 bits
    uint u = __builtin_bit_cast(uint, f);
    u += 0x7fff + ((u >> 16) & 1);
    return (ushort)(u >> 16);
}
__device__ __forceinline__ float bf2f(ushort h) {
    return __builtin_bit_cast(float, (uint)h << 16);
}
__device__ __forceinline__ uint pk(float f) {       // hi|lo<<16 packed split
    ushort h = f2bf(f);
    return (uint)h | ((uint)f2bf(f - bf2f(h)) << 16);
}
__device__ __forceinline__ uint4 pack4(float4 d) {
    return make_uint4(pk(d.x), pk(d.y), pk(d.z), pk(d.w));
}

// ---------------- weight prep ----------------
// wfrag1: conv1 weights, B-frag order, K padded 50->64: ((c*4+s)*2+split)*64+lane
// wfrag2: conv2 weights, B-frag order, K padded 25->32: ((c*2+ks)*2+split)*64+lane
__global__ void k_prep_w(const float* __restrict__ c1w, const float* __restrict__ c2w,
                         ushort* __restrict__ wfrag1, ushort* __restrict__ wfrag2) {
    int i = blockIdx.x * 256 + threadIdx.x;
    if (i < 6144) {
        int lane = i & 63, r = i >> 6;
        int split = r & 1, s = (r >> 1) & 3, c = r >> 3;
        int oc = lane & 31, kbase = s * 16 + (lane >> 5) * 8;
        ushort o8[8];
#pragma unroll
        for (int j = 0; j < 8; ++j) {
            int kk = kbase + j;
            float w = (kk < 50) ? c1w[oc * 600 + c * 50 + kk] : 0.f;
            ushort hb = f2bf(w);
            o8[j] = split ? f2bf(w - bf2f(hb)) : hb;
        }
        ushort4* dst = reinterpret_cast<ushort4*>(wfrag1) + (size_t)i * 2;
        dst[0] = make_ushort4(o8[0], o8[1], o8[2], o8[3]);
        dst[1] = make_ushort4(o8[4], o8[5], o8[6], o8[7]);
    } else if (i < 14336) {
        int j = i - 6144;
        int lane = j & 63, r = j >> 6;
        int split = r & 1, ks = (r >> 1) & 1, c = r >> 2;
        int oc = lane & 31, kbase = ks * 16 + (lane >> 5) * 8;
        ushort o8[8];
#pragma unroll
        for (int jj = 0; jj < 8; ++jj) {
            int kk = kbase + jj;
            float w = (kk < 25) ? c2w[oc * 800 + c * 25 + kk] : 0.f;
            ushort hb = f2bf(w);
            o8[jj] = split ? f2bf(w - bf2f(hb)) : hb;
        }
        ushort4* dst = reinterpret_cast<ushort4*>(wfrag2) + (size_t)j * 2;
        dst[0] = make_ushort4(o8[0], o8[1], o8[2], o8[3]);
        dst[1] = make_ushort4(o8[4], o8[5], o8[6], o8[7]);
    }
}

// A-fragment compute over channel range: packed-uint LDS, b64 reads, v_perm unpack,
// 3 independent MFMA chains.
__device__ __forceinline__ void conv1_compute(const uint (*xs)[1344], const uint4* wf4,
                                              int c0, int c1, int abase, int lane,
                                              f32x16& hh, f32x16& hl, f32x16& lh) {
    for (int c = c0; c < c1; ++c) {
        const uint* xc = xs[c];
        const uint4* wfc = wf4 + (size_t)c * 512 + lane;
#pragma unroll
        for (int s = 0; s < 4; ++s) {
            const int idx = abase + s * 16;    // even -> 8B aligned
            uint2 p0 = *reinterpret_cast<const uint2*>(&xc[idx]);
            uint2 p1 = *reinterpret_cast<const uint2*>(&xc[idx + 2]);
            uint2 p2 = *reinterpret_cast<const uint2*>(&xc[idx + 4]);
            uint2 p3 = *reinterpret_cast<const uint2*>(&xc[idx + 6]);
            union { s16x8 v; uint u[4]; } ah, al, bh, bl;
            ah.u[0] = __builtin_amdgcn_perm(p0.y, p0.x, 0x05040100u);
            al.u[0] = __builtin_amdgcn_perm(p0.y, p0.x, 0x07060302u);
            ah.u[1] = __builtin_amdgcn_perm(p1.y, p1.x, 0x05040100u);
            al.u[1] = __builtin_amdgcn_perm(p1.y, p1.x, 0x07060302u);
            ah.u[2] = __builtin_amdgcn_perm(p2.y, p2.x, 0x05040100u);
            al.u[2] = __builtin_amdgcn_perm(p2.y, p2.x, 0x07060302u);
            ah.u[3] = __builtin_amdgcn_perm(p3.y, p3.x, 0x05040100u);
            al.u[3] = __builtin_amdgcn_perm(p3.y, p3.x, 0x07060302u);
            uint4 bq = wfc[s * 128];
            uint4 lq = wfc[s * 128 + 64];
            bh.u[0] = bq.x; bh.u[1] = bq.y; bh.u[2] = bq.z; bh.u[3] = bq.w;
            bl.u[0] = lq.x; bl.u[1] = lq.y; bl.u[2] = lq.z; bl.u[3] = lq.w;
            hh = __builtin_amdgcn_mfma_f32_32x32x16_bf16(ah.v, bh.v, hh, 0, 0, 0);
            hl = __builtin_amdgcn_mfma_f32_32x32x16_bf16(ah.v, bl.v, hl, 0, 0, 0);
            lh = __builtin_amdgcn_mfma_f32_32x32x16_bf16(al.v, bh.v, lh, 0, 0, 0);
        }
    }
}

// ---------------- conv1 via split-bf16 MFMA + bias + BN1 stats ----------------
// grid (4, B), 256 thr = 4 waves; wave = one 32x32 C-tile. All 12 channels staged
// once (packed uint, 63KB), two-half stage with raw s_barrier (no vmcnt drain).
__global__ __launch_bounds__(256) void k_conv1(const float* __restrict__ x,
                                               const ushort* __restrict__ wfrag,
                                               const float* __restrict__ c1b,
                                               float* __restrict__ y1,
                                               float* __restrict__ raw1) {
    __shared__ uint xs[C_IN][1344];            // 64512 B packed hi|lo
    __shared__ float redS[4][32], redQ[4][32];
    const int chunk = blockIdx.x, b = blockIdx.y, tid = threadIdx.x;
    const int t0 = chunk * 128;
    const int v4max = min(336, (5000 - 10 * t0) >> 2);   // chunk3: 290
    const float4* xb4 = reinterpret_cast<const float4*>(x + (size_t)b * (C_IN * L_IN) + 10 * t0);

    // issue all global loads up front (half A: slots 0..2047, half B: 2048..4031)
    float4 rA[8], rB[8];
#pragma unroll
    for (int i = 0; i < 8; ++i) {
        const int v = tid + i * 256;
        const int c = v / 336, i4 = v - c * 336;
        rA[i] = make_float4(0, 0, 0, 0);
        if (i4 < v4max) rA[i] = xb4[c * 1250 + i4];
    }
#pragma unroll
    for (int i = 0; i < 8; ++i) {
        const int v = tid + 2048 + i * 256;
        const int c = v / 336, i4 = v - c * 336;
        rB[i] = make_float4(0, 0, 0, 0);
        if (v < 4032 && i4 < v4max) rB[i] = xb4[c * 1250 + i4];
    }

    uint4* xs4 = reinterpret_cast<uint4*>(&xs[0][0]);
#pragma unroll
    for (int i = 0; i < 8; ++i) xs4[tid + i * 256] = pack4(rA[i]);
    asm volatile("s_waitcnt lgkmcnt(0)" ::: "memory");
    __builtin_amdgcn_s_barrier();              // rB loads stay in flight
    __builtin_amdgcn_sched_barrier(0);

    const int lane = tid & 63, wv = tid >> 6;
    const int cl = lane & 31;
    const int kgrp = lane >> 5;
    const int abase = 10 * (wv * 32 + cl) + kgrp * 8;

    f32x16 hh, hl, lh;
#pragma unroll
    for (int i = 0; i < 16; ++i) { hh[i] = 0.f; hl[i] = 0.f; lh[i] = 0.f; }
    const uint4* wf4 = reinterpret_cast<const uint4*>(wfrag);

    conv1_compute(xs, wf4, 0, 6, abase, lane, hh, hl, lh);

#pragma unroll
    for (int i = 0; i < 8; ++i) {
        const int v = tid + 2048 + i * 256;
        if (v < 4032) xs4[v] = pack4(rB[i]);   // compiler inserts vmcnt for rB
    }
    asm volatile("s_waitcnt lgkmcnt(0)" ::: "memory");
    __builtin_amdgcn_s_barrier();
    __builtin_amdgcn_sched_barrier(0);

    conv1_compute(xs, wf4, 6, 12, abase, lane, hh, hl, lh);

    // epilogue: sum chains, bias, store, BN1 stats
    const float bias = c1b[cl];
    float sum = 0.f, sq = 0.f;
    float* yb = y1 + ((size_t)b * C1 + cl) * L1;
#pragma unroll
    for (int q = 0; q < 4; ++q) {
        const int trow = t0 + wv * 32 + 8 * q + 4 * kgrp;
        float4 st;
        st.x = hh[4*q+0] + hl[4*q+0] + lh[4*q+0] + bias;
        st.y = hh[4*q+1] + hl[4*q+1] + lh[4*q+1] + bias;
        st.z = hh[4*q+2] + hl[4*q+2] + lh[4*q+2] + bias;
        st.w = hh[4*q+3] + hl[4*q+3] + lh[4*q+3] + bias;
        if (trow < L1) {
            *reinterpret_cast<float4*>(yb + trow) = st;
            sum += st.x + st.y + st.z + st.w;
            sq  += st.x * st.x + st.y * st.y + st.z * st.z + st.w * st.w;
        }
    }
    sum += __shfl_xor(sum, 32);
    sq  += __shfl_xor(sq, 32);
    if (lane < 32) { redS[wv][cl] = sum; redQ[wv][cl] = sq; }
    __syncthreads();
    if (tid < 64) {
        int o = tid & 31, isQ = tid >> 5;
        float v = isQ ? (redQ[0][o] + redQ[1][o] + redQ[2][o] + redQ[3][o])
                      : (redS[0][o] + redS[1][o] + redS[2][o] + redS[3][o]);
        atomicAdd(&raw1[(isQ ? 1024 : 0) + o * 16], v);
    }
}

// ---------------- conv2 via split-bf16 MFMA (+inline BN1 finalize+apply+relu, BN2 stats) ----------------
// grid B, 192 thr = 3 waves; wave wv owns 32x32 C-tile. 3 independent MFMA chains.
__global__ __launch_bounds__(192) void k_conv2(const float* __restrict__ y1,
                                               const ushort* __restrict__ wfrag2,
                                               const float* __restrict__ c2b,
                                               const float* __restrict__ raw1,
                                               const float* __restrict__ bn1g,
                                               const float* __restrict__ bn1b,
                                               float* __restrict__ y2,
                                               float* __restrict__ raw2) {
    __shared__ uint xs[C1][512];         // 64 KB packed
    __shared__ float fin[64];
    __shared__ float redS[3][32], redQ[3][32];
    const int b = blockIdx.x, tid = threadIdx.x;

    if (tid < 32) {                      // BN1 finalize (redundant per block, cheap)
        const float cnt = 1.f / (float)(B * L1);
        float mean = raw1[tid * 16] * cnt;
        float var = raw1[1024 + tid * 16] * cnt - mean * mean;
        float sc = bn1g[tid] * rsqrtf(var + EPS);
        fin[tid] = sc;
        fin[32 + tid] = bn1b[tid] - mean * sc;
    }
    __syncthreads();

    // stage: y1[b] -> BN+relu -> packed uints, rows padded 496->512 with zeros
    const float4* src = reinterpret_cast<const float4*>(y1 + (size_t)b * (C1 * L1));
    for (int v = tid; v < C1 * 128; v += 192) {
        const int c = v >> 7, i4 = v & 127;
        uint4 o = make_uint4(0, 0, 0, 0);
        if (i4 < 124) {
            const float sc = fin[c], sh = fin[32 + c];
            float4 d = src[c * 124 + i4];
            float e0 = fmaxf(fmaf(d.x, sc, sh), 0.f);
            float e1 = fmaxf(fmaf(d.y, sc, sh), 0.f);
            float e2 = fmaxf(fmaf(d.z, sc, sh), 0.f);
            float e3 = fmaxf(fmaf(d.w, sc, sh), 0.f);
            o = make_uint4(pk(e0), pk(e1), pk(e2), pk(e3));
        }
        *reinterpret_cast<uint4*>(&xs[c][4 * i4]) = o;
    }
    __syncthreads();

    const int lane = tid & 63, wv = tid / 64;
    const int cl = lane & 31;
    const int kgrp = lane >> 5;
    const int tbase = 5 * (wv * 32 + cl) + kgrp * 8;

    f32x16 hh, hl, lh;
#pragma unroll
    for (int i = 0; i < 16; ++i) { hh[i] = 0.f; hl[i] = 0.f; lh[i] = 0.f; }
    const uint4* wf4 = reinterpret_cast<const uint4*>(wfrag2);

    for (int c = 0; c < C1; ++c) {
        const uint* xc = xs[c];
        const uint4* wfc = wf4 + (size_t)c * 256 + lane;
#pragma unroll
        for (int ks = 0; ks < 2; ++ks) {
            const int idx = tbase + ks * 16;
            uint u0 = xc[idx + 0], u1 = xc[idx + 1], u2 = xc[idx + 2], u3 = xc[idx + 3];
            uint u4 = xc[idx + 4], u5 = xc[idx + 5], u6 = xc[idx + 6], u7 = xc[idx + 7];
            union { s16x8 v; uint u[4]; } ah, al, bh, bl;
            ah.u[0] = __builtin_amdgcn_perm(u1, u0, 0x05040100u);
            al.u[0] = __builtin_amdgcn_perm(u1, u0, 0x07060302u);
            ah.u[1] = __builtin_amdgcn_perm(u3, u2, 0x05040100u);
            al.u[1] = __builtin_amdgcn_perm(u3, u2, 0x07060302u);
            ah.u[2] = __builtin_amdgcn_perm(u5, u4, 0x05040100u);
            al.u[2] = __builtin_amdgcn_perm(u5, u4, 0x07060302u);
            ah.u[3] = __builtin_amdgcn_perm(u7, u6, 0x05040100u);
            al.u[3] = __builtin_amdgcn_perm(u7, u6, 0x07060302u);
            uint4 bq = wfc[ks * 128];
            uint4 lq = wfc[ks * 128 + 64];
            bh.u[0] = bq.x; bh.u[1] = bq.y; bh.u[2] = bq.z; bh.u[3] = bq.w;
            bl.u[0] = lq.x; bl.u[1] = lq.y; bl.u[2] = lq.z; bl.u[3] = lq.w;
            hh = __builtin_amdgcn_mfma_f32_32x32x16_bf16(ah.v, bh.v, hh, 0, 0, 0);
            hl = __builtin_amdgcn_mfma_f32_32x32x16_bf16(ah.v, bl.v, hl, 0, 0, 0);
            lh = __builtin_amdgcn_mfma_f32_32x32x16_bf16(al.v, bh.v, lh, 0, 0, 0);
        }
    }

    // epilogue: bias, stores to y2[b][t][oc], BN2 stats
    const float bias = c2b[cl];
    float sum = 0.f, sq = 0.f;
#pragma unroll
    for (int q = 0; q < 4; ++q) {
#pragma unroll
        for (int j = 0; j < 4; ++j) {
            const int t = wv * 32 + 8 * q + 4 * kgrp + j;
            const float v = hh[4*q+j] + hl[4*q+j] + lh[4*q+j] + bias;
            if (t < L2) {
                y2[((size_t)b * L2 + t) * NF + cl] = v;
                sum += v; sq += v * v;
            }
        }
    }
    sum += __shfl_xor(sum, 32);
    sq  += __shfl_xor(sq, 32);
    if (lane < 32) { redS[wv][cl] = sum; redQ[wv][cl] = sq; }
    __syncthreads();
    if (tid < 64) {
        int o = tid & 31, isQ = tid >> 5;
        float v = isQ ? (redQ[0][o] + redQ[1][o] + redQ[2][o])
                      : (redS[0][o] + redS[1][o] + redS[2][o]);
        atomicAdd(&raw2[(isQ ? 1024 : 0) + o * 16], v);
    }
}

// ---------------- BN2 finalize (inline) + relu, input proj, LN1, fold Wh ----------------
// grid exactly 190 blocks x 256 (= B*T threads). xt2 layout [T][B][HID].
__global__ __launch_bounds__(256) void k_proj(const float* __restrict__ y2,
                                              const float* __restrict__ raw2,
                                              const float* __restrict__ bn2g,
                                              const float* __restrict__ bn2b,
                                              const float* __restrict__ Wi,
                                              const float* __restrict__ bi,
                                              const float* __restrict__ ln1g,
                                              const float* __restrict__ ln1b,
                                              const float* __restrict__ Wh,
                                              const float* __restrict__ bh,
                                              float* __restrict__ xt2) {
    __shared__ float fin[64];
    if (threadIdx.x < 32) {
        const float cnt = 1.f / (float)(B * L2);
        float mean = raw2[threadIdx.x * 16] * cnt;
        float var = raw2[1024 + threadIdx.x * 16] * cnt - mean * mean;
        float sc = bn2g[threadIdx.x] * rsqrtf(var + EPS);
        fin[threadIdx.x] = sc;
        fin[32 + threadIdx.x] = bn2b[threadIdx.x] - mean * sc;
    }
    __syncthreads();

    const int r = blockIdx.x * 256 + threadIdx.x;
    const int b = r / 95, t = r - b * 95;

    const float4* row = reinterpret_cast<const float4*>(y2 + (size_t)r * NF);
    float u[NF];
#pragma unroll
    for (int f4 = 0; f4 < 8; ++f4) {
        float4 v = row[f4];
        u[4*f4]   = fmaxf(fmaf(v.x, fin[4*f4],   fin[32 + 4*f4]),   0.f);
        u[4*f4+1] = fmaxf(fmaf(v.y, fin[4*f4+1], fin[32 + 4*f4+1]), 0.f);
        u[4*f4+2] = fmaxf(fmaf(v.z, fin[4*f4+2], fin[32 + 4*f4+2]), 0.f);
        u[4*f4+3] = fmaxf(fmaf(v.w, fin[4*f4+3], fin[32 + 4*f4+3]), 0.f);
    }
    float xln[LAT];
    float s = 0.f, q = 0.f;
#pragma unroll
    for (int l = 0; l < LAT; ++l) {
        float a = bi[l];
#pragma unroll
        for (int f = 0; f < NF; ++f) a = fmaf(u[f], Wi[l * NF + f], a);
        xln[l] = a; s += a; q += a * a;
    }
    const float m = s * (1.f / LAT);
    const float inv = rsqrtf(q * (1.f / LAT) - m * m + EPS);
#pragma unroll
    for (int l = 0; l < LAT; ++l) xln[l] = (xln[l] - m) * inv * ln1g[l] + ln1b[l];

    float4* dst = reinterpret_cast<float4*>(xt2 + ((size_t)t * B + b) * HID);
#pragma unroll
    for (int j4 = 0; j4 < 16; ++j4) {
        float4 o4;
        float a0 = bh[4*j4], a1 = bh[4*j4+1], a2 = bh[4*j4+2], a3 = bh[4*j4+3];
#pragma unroll
        for (int l = 0; l < LAT; ++l) {
            float xl = xln[l];
            a0 = fmaf(xl, Wh[(4*j4)   * LAT + l], a0);
            a1 = fmaf(xl, Wh[(4*j4+1) * LAT + l], a1);
            a2 = fmaf(xl, Wh[(4*j4+2) * LAT + l], a2);
            a3 = fmaf(xl, Wh[(4*j4+3) * LAT + l], a3);
        }
        o4.x = a0; o4.y = a1; o4.z = a2; o4.w = a3;
        dst[j4] = o4;
    }
}

// ---------------- RNN scan + pooled mean + final linear ----------------
// 1 wave per batch row. LN2 folded into Wr-dot; multi-accumulator dots.
__global__ __launch_bounds__(64) void k_rnn(const float* __restrict__ xt2,
                                            const float* __restrict__ Wh,
                                            const float* __restrict__ ln2g,
                                            const float* __restrict__ ln2b,
                                            const float* __restrict__ Wr,
                                            const float* __restrict__ br,
                                            const float* __restrict__ Wo,
                                            const float* __restrict__ bo,
                                            float* __restrict__ out) {
    __shared__ __align__(16) float aS[64];
    __shared__ __align__(16) float hS[32];
    const int lane = threadIdx.x;
    const int b = blockIdx.x;
    const int l = lane & 31;

    float whv[LAT];
#pragma unroll
    for (int i = 0; i < LAT; ++i) whv[i] = Wh[lane * LAT + i];

    float wg[HID];
    float S1 = 0.f, S2 = br[l];
#pragma unroll
    for (int j = 0; j < HID; ++j) {
        float w = Wr[l * HID + j];
        wg[j] = w * ln2g[j];
        S1 += wg[j];
        S2 = fmaf(w, ln2b[j], S2);
    }

    float hfull[LAT];
#pragma unroll
    for (int i = 0; i < LAT; ++i) hfull[i] = 0.f;
    float pooled = 0.f;
    float xq = xt2[(size_t)b * HID + lane];

    for (int t = 0; t < T; ++t) {
        float xq_next = 0.f;
        if (t + 1 < T) xq_next = xt2[((size_t)(t + 1) * B + b) * HID + lane];

        float a0 = xq, a1 = 0.f, a2c = 0.f, a3c = 0.f;
#pragma unroll
        for (int i = 0; i < 8; ++i) {
            a0  = fmaf(hfull[4*i+0], whv[4*i+0], a0);
            a1  = fmaf(hfull[4*i+1], whv[4*i+1], a1);
            a2c = fmaf(hfull[4*i+2], whv[4*i+2], a2c);
            a3c = fmaf(hfull[4*i+3], whv[4*i+3], a3c);
        }
        const float a = fmaxf((a0 + a1) + (a2c + a3c), 0.f);

        aS[lane] = a;
        asm volatile("s_waitcnt lgkmcnt(0)" ::: "memory");

        float d0 = 0.f, d1 = 0.f, d2 = 0.f, d3 = 0.f;
#pragma unroll
        for (int i = 0; i < 16; ++i) {
            float4 v = reinterpret_cast<const float4*>(aS)[i];
            d0 = fmaf(v.x, wg[4*i+0], d0); d1 = fmaf(v.y, wg[4*i+1], d1);
            d2 = fmaf(v.z, wg[4*i+2], d2); d3 = fmaf(v.w, wg[4*i+3], d3);
        }
        float s = a, q = a * a;
#pragma unroll
        for (int off = 32; off >= 1; off >>= 1) { s += __shfl_xor(s, off); q += __shfl_xor(q, off); }
        const float m = s * (1.f / HID);
        const float inv = __builtin_amdgcn_rsqf(q * (1.f / HID) - m * m + EPS);
        const float dot = (d0 + d1) + (d2 + d3);
        const float a2v = fmaf(inv, dot - m * S1, S2);

        const float z = __builtin_amdgcn_exp2f(2.8853900817779268f * a2v);
        const float h = 1.f - 2.f * __builtin_amdgcn_rcpf(z + 1.f);
        pooled += h;

        if (lane < 32) hS[lane] = h;
        asm volatile("s_waitcnt lgkmcnt(0)" ::: "memory");
#pragma unroll
        for (int i = 0; i < 8; ++i) {
            float4 hv = reinterpret_cast<const float4*>(hS)[i];
            hfull[4*i] = hv.x; hfull[4*i+1] = hv.y; hfull[4*i+2] = hv.z; hfull[4*i+3] = hv.w;
        }
        xq = xq_next;
    }
    pooled *= (1.f / T);
    if (lane < 32) aS[lane] = pooled;
    asm volatile("s_waitcnt lgkmcnt(0)" ::: "memory");

    float wov[LAT];
#pragma unroll
    for (int i = 0; i < LAT; ++i) wov[i] = Wo[l * LAT + i];
    float b0 = bo[l], b1 = 0.f, b2 = 0.f, b3 = 0.f;
#pragma unroll
    for (int i = 0; i < 8; ++i) {
        float4 pv = reinterpret_cast<const float4*>(aS)[i];
        b0 = fmaf(pv.x, wov[4*i+0], b0); b1 = fmaf(pv.y, wov[4*i+1], b1);
        b2 = fmaf(pv.z, wov[4*i+2], b2); b3 = fmaf(pv.w, wov[4*i+3], b3);
    }
    if (lane < 32) out[(size_t)b * LAT + l] = (b0 + b1) + (b2 + b3);
}

extern "C" void kernel_launch(void* const* d_in, const int* in_sizes, int n_in,
                              void* d_out, int out_size, void* d_ws, size_t ws_size,
                              hipStream_t stream) {
    const float* x    = (const float*)d_in[0];
    const float* c1w  = (const float*)d_in[1];
    const float* c1b  = (const float*)d_in[2];
    const float* bn1g = (const float*)d_in[3];
    const float* bn1b = (const float*)d_in[4];
    const float* c2w  = (const float*)d_in[5];
    const float* c2b  = (const float*)d_in[6];
    const float* bn2g = (const float*)d_in[7];
    const float* bn2b = (const float*)d_in[8];
    const float* Wi   = (const float*)d_in[9];
    const float* bi   = (const float*)d_in[10];
    const float* ln1g = (const float*)d_in[11];
    const float* ln1b = (const float*)d_in[12];
    const float* Wh   = (const float*)d_in[13];
    const float* bh   = (const float*)d_in[14];
    const float* ln2g = (const float*)d_in[15];
    const float* ln2b = (const float*)d_in[16];
    const float* Wr   = (const float*)d_in[17];
    const float* br   = (const float*)d_in[18];
    const float* Wo   = (const float*)d_in[19];
    const float* bo   = (const float*)d_in[20];

    float* ws = (float*)d_ws;
    float* raw1 = ws;                      // 2048 (S at o*16, Q at 1024+o*16)
    float* raw2 = ws + 2048;               // 2048
    ushort* wfrag1 = (ushort*)(ws + 4096); // 49152 ushorts -> ends 28672
    ushort* wfrag2 = (ushort*)(ws + 28672);// 65536 ushorts -> ends 61440
    float* y1   = ws + 61440;              // 8126464 -> ends 8187904
    float* y2   = ws + 8187904;            // 1556480 -> ends 9744384
    float* xt2  = y1;                      // alias y1 (dead after conv2)
    float* out  = (float*)d_out;

    hipMemsetAsync(raw1, 0, 4096 * sizeof(float), stream);
    k_prep_w<<<56, 256, 0, stream>>>(c1w, c2w, wfrag1, wfrag2);
    k_conv1<<<dim3(4, B), 256, 0, stream>>>(x, wfrag1, c1b, y1, raw1);
    k_conv2<<<B, 192, 0, stream>>>(y1, wfrag2, c2b, raw1, bn1g, bn1b, y2, raw2);
    k_proj<<<190, 256, 0, stream>>>(y2, raw2, bn2g, bn2b, Wi, bi, ln1g, ln1b, Wh, bh, xt2);
    k_rnn<<<B, 64, 0, stream>>>(xt2, Wh, ln2g, ln2b, Wr, br, Wo, bo, out);
}

// Round 7
// 228.771 us; speedup vs baseline: 1.1258x; 1.1258x over previous
//
#include <hip/hip_runtime.h>

#define EPS 1e-5f

#define B    512
#define C_IN 12
#define L_IN 5000
#define C1   32
#define L1   496   // (5000-50)/10+1
#define NF   32
#define L2   95    // (496-25)/5+1
#define LAT  32
#define HID  64
#define T    L2

typedef short s16x8 __attribute__((ext_vector_type(8)));
typedef float f32x16 __attribute__((ext_vector_type(16)));

__device__ __forceinline__ ushort f2bf(float f) {   // RNE float->bf16 bits
    uint u = __builtin_bit_cast(uint, f);
    u += 0x7fff + ((u >> 16) & 1);
    return (ushort)(u >> 16);
}
__device__ __forceinline__ float bf2f(ushort h) {
    return __builtin_bit_cast(float, (uint)h << 16);
}
__device__ __forceinline__ uint pk(float f) {       // hi|lo<<16 packed split
    ushort h = f2bf(f);
    return (uint)h | ((uint)f2bf(f - bf2f(h)) << 16);
}
__device__ __forceinline__ uint4 pack4(float4 d) {
    return make_uint4(pk(d.x), pk(d.y), pk(d.z), pk(d.w));
}

// ---------------- weight prep ----------------
// wfrag1: conv1 weights, B-frag order, K padded 50->64: ((c*4+s)*2+split)*64+lane
// wfrag2: conv2 weights, B-frag order, K padded 25->32: ((c*2+ks)*2+split)*64+lane
__global__ void k_prep_w(const float* __restrict__ c1w, const float* __restrict__ c2w,
                         ushort* __restrict__ wfrag1, ushort* __restrict__ wfrag2) {
    int i = blockIdx.x * 256 + threadIdx.x;
    if (i < 6144) {
        int lane = i & 63, r = i >> 6;
        int split = r & 1, s = (r >> 1) & 3, c = r >> 3;
        int oc = lane & 31, kbase = s * 16 + (lane >> 5) * 8;
        ushort o8[8];
#pragma unroll
        for (int j = 0; j < 8; ++j) {
            int kk = kbase + j;
            float w = (kk < 50) ? c1w[oc * 600 + c * 50 + kk] : 0.f;
            ushort hb = f2bf(w);
            o8[j] = split ? f2bf(w - bf2f(hb)) : hb;
        }
        ushort4* dst = reinterpret_cast<ushort4*>(wfrag1) + (size_t)i * 2;
        dst[0] = make_ushort4(o8[0], o8[1], o8[2], o8[3]);
        dst[1] = make_ushort4(o8[4], o8[5], o8[6], o8[7]);
    } else if (i < 14336) {
        int j = i - 6144;
        int lane = j & 63, r = j >> 6;
        int split = r & 1, ks = (r >> 1) & 1, c = r >> 2;
        int oc = lane & 31, kbase = ks * 16 + (lane >> 5) * 8;
        ushort o8[8];
#pragma unroll
        for (int jj = 0; jj < 8; ++jj) {
            int kk = kbase + jj;
            float w = (kk < 25) ? c2w[oc * 800 + c * 25 + kk] : 0.f;
            ushort hb = f2bf(w);
            o8[jj] = split ? f2bf(w - bf2f(hb)) : hb;
        }
        ushort4* dst = reinterpret_cast<ushort4*>(wfrag2) + (size_t)j * 2;
        dst[0] = make_ushort4(o8[0], o8[1], o8[2], o8[3]);
        dst[1] = make_ushort4(o8[4], o8[5], o8[6], o8[7]);
    }
}

// A-fragment compute over 6 channels: packed-uint LDS, b64 reads, v_perm unpack,
// 3 independent MFMA chains.
__device__ __forceinline__ void conv1_compute(const uint (*xs)[1344], const uint4* wf4,
                                              int c0, int abase, int lane,
                                              f32x16& hh, f32x16& hl, f32x16& lh) {
    for (int cc = 0; cc < 6; ++cc) {
        const int c = c0 + cc;
        const uint* xc = xs[c];
        const uint4* wfc = wf4 + (size_t)c * 512 + lane;
#pragma unroll
        for (int s = 0; s < 4; ++s) {
            const int idx = abase + s * 16;    // even -> 8B aligned
            uint2 p0 = *reinterpret_cast<const uint2*>(&xc[idx]);
            uint2 p1 = *reinterpret_cast<const uint2*>(&xc[idx + 2]);
            uint2 p2 = *reinterpret_cast<const uint2*>(&xc[idx + 4]);
            uint2 p3 = *reinterpret_cast<const uint2*>(&xc[idx + 6]);
            union { s16x8 v; uint u[4]; } ah, al, bh, bl;
            ah.u[0] = __builtin_amdgcn_perm(p0.y, p0.x, 0x05040100u);
            al.u[0] = __builtin_amdgcn_perm(p0.y, p0.x, 0x07060302u);
            ah.u[1] = __builtin_amdgcn_perm(p1.y, p1.x, 0x05040100u);
            al.u[1] = __builtin_amdgcn_perm(p1.y, p1.x, 0x07060302u);
            ah.u[2] = __builtin_amdgcn_perm(p2.y, p2.x, 0x05040100u);
            al.u[2] = __builtin_amdgcn_perm(p2.y, p2.x, 0x07060302u);
            ah.u[3] = __builtin_amdgcn_perm(p3.y, p3.x, 0x05040100u);
            al.u[3] = __builtin_amdgcn_perm(p3.y, p3.x, 0x07060302u);
            uint4 bq = wfc[s * 128];
            uint4 lq = wfc[s * 128 + 64];
            bh.u[0] = bq.x; bh.u[1] = bq.y; bh.u[2] = bq.z; bh.u[3] = bq.w;
            bl.u[0] = lq.x; bl.u[1] = lq.y; bl.u[2] = lq.z; bl.u[3] = lq.w;
            hh = __builtin_amdgcn_mfma_f32_32x32x16_bf16(ah.v, bh.v, hh, 0, 0, 0);
            hl = __builtin_amdgcn_mfma_f32_32x32x16_bf16(ah.v, bl.v, hl, 0, 0, 0);
            lh = __builtin_amdgcn_mfma_f32_32x32x16_bf16(al.v, bh.v, lh, 0, 0, 0);
        }
    }
}

// ---------------- conv1 via split-bf16 MFMA + bias + BN1 stats ----------------
// grid (4, B), 512 thr = 8 waves. Waves 0-3: t-tiles 0-3 x channels 0-5;
// waves 4-7: same tiles x channels 6-11. Partials combined via LDS. One stage,
// plain barriers (nothing in flight across them), 2 blocks/CU.
__global__ __launch_bounds__(512, 4) void k_conv1(const float* __restrict__ x,
                                                  const ushort* __restrict__ wfrag,
                                                  const float* __restrict__ c1b,
                                                  float* __restrict__ y1,
                                                  float* __restrict__ raw1) {
    __shared__ uint xs[C_IN][1344];            // 64512 B packed hi|lo
    __shared__ float redS[4][32], redQ[4][32];
    const int chunk = blockIdx.x, b = blockIdx.y, tid = threadIdx.x;
    const int t0 = chunk * 128;
    const int v4max = min(336, (5000 - 10 * t0) >> 2);   // chunk3: 290
    const float4* xb4 = reinterpret_cast<const float4*>(x + (size_t)b * (C_IN * L_IN) + 10 * t0);

    // stage all 12 channels: 4032 uint4 slots, 2 rounds of 4 per thread
    uint4* xs4 = reinterpret_cast<uint4*>(&xs[0][0]);
#pragma unroll
    for (int r = 0; r < 2; ++r) {
        float4 rg[4];
#pragma unroll
        for (int i = 0; i < 4; ++i) {
            const int v = tid + (r * 4 + i) * 512;
            const int c = v / 336, i4 = v - c * 336;
            rg[i] = make_float4(0, 0, 0, 0);
            if (v < 4032 && i4 < v4max) rg[i] = xb4[c * 1250 + i4];
        }
#pragma unroll
        for (int i = 0; i < 4; ++i) {
            const int v = tid + (r * 4 + i) * 512;
            if (v < 4032) xs4[v] = pack4(rg[i]);
        }
    }
    __syncthreads();

    const int lane = tid & 63, wv = tid >> 6;
    const int g = wv >> 2;                     // K-group (0: ch0-5, 1: ch6-11)
    const int tw = wv & 3;                     // t-tile
    const int cl = lane & 31;
    const int kgrp = lane >> 5;
    const int abase = 10 * (tw * 32 + cl) + kgrp * 8;

    f32x16 hh, hl, lh;
#pragma unroll
    for (int i = 0; i < 16; ++i) { hh[i] = 0.f; hl[i] = 0.f; lh[i] = 0.f; }
    const uint4* wf4 = reinterpret_cast<const uint4*>(wfrag);

    conv1_compute(xs, wf4, g * 6, abase, lane, hh, hl, lh);

    f32x16 tot;
#pragma unroll
    for (int i = 0; i < 16; ++i) tot[i] = hh[i] + hl[i] + lh[i];

    // combine K-groups: g1 writes partials to LDS (reuse xs), g0 adds
    __syncthreads();
    float4* pr = reinterpret_cast<float4*>(&xs[0][0]);   // [tile][i4][lane]
    if (g == 1) {
#pragma unroll
        for (int i4 = 0; i4 < 4; ++i4)
            pr[tw * 256 + i4 * 64 + lane] =
                make_float4(tot[4*i4], tot[4*i4+1], tot[4*i4+2], tot[4*i4+3]);
    }
    __syncthreads();

    float sum = 0.f, sq = 0.f;
    if (g == 0) {
        const float bias = c1b[cl];
        float* yb = y1 + ((size_t)b * C1 + cl) * L1;
#pragma unroll
        for (int q = 0; q < 4; ++q) {
            float4 p = pr[tw * 256 + q * 64 + lane];
            const int trow = t0 + tw * 32 + 8 * q + 4 * kgrp;
            float4 st;
            st.x = tot[4*q+0] + p.x + bias;
            st.y = tot[4*q+1] + p.y + bias;
            st.z = tot[4*q+2] + p.z + bias;
            st.w = tot[4*q+3] + p.w + bias;
            if (trow < L1) {
                *reinterpret_cast<float4*>(yb + trow) = st;
                sum += st.x + st.y + st.z + st.w;
                sq  += st.x * st.x + st.y * st.y + st.z * st.z + st.w * st.w;
            }
        }
        sum += __shfl_xor(sum, 32);
        sq  += __shfl_xor(sq, 32);
        if (lane < 32) { redS[tw][cl] = sum; redQ[tw][cl] = sq; }
    }
    __syncthreads();
    if (tid < 64) {
        int o = tid & 31, isQ = tid >> 5;
        float v = isQ ? (redQ[0][o] + redQ[1][o] + redQ[2][o] + redQ[3][o])
                      : (redS[0][o] + redS[1][o] + redS[2][o] + redS[3][o]);
        atomicAdd(&raw1[(isQ ? 1024 : 0) + o * 16], v);
    }
}

// ---------------- conv2 via split-bf16 MFMA (+inline BN1 finalize+apply+relu, BN2 stats) ----------------
// grid B, 384 thr = 6 waves. Waves 0-2: tiles x ch 0-15; waves 3-5: tiles x ch 16-31.
__global__ __launch_bounds__(384, 3) void k_conv2(const float* __restrict__ y1,
                                                  const ushort* __restrict__ wfrag2,
                                                  const float* __restrict__ c2b,
                                                  const float* __restrict__ raw1,
                                                  const float* __restrict__ bn1g,
                                                  const float* __restrict__ bn1b,
                                                  float* __restrict__ y2,
                                                  float* __restrict__ raw2) {
    __shared__ uint xs[C1][512];         // 64 KB packed
    __shared__ float fin[64];
    __shared__ float redS[3][32], redQ[3][32];
    const int b = blockIdx.x, tid = threadIdx.x;

    if (tid < 32) {                      // BN1 finalize (redundant per block, cheap)
        const float cnt = 1.f / (float)(B * L1);
        float mean = raw1[tid * 16] * cnt;
        float var = raw1[1024 + tid * 16] * cnt - mean * mean;
        float sc = bn1g[tid] * rsqrtf(var + EPS);
        fin[tid] = sc;
        fin[32 + tid] = bn1b[tid] - mean * sc;
    }
    __syncthreads();

    // stage: y1[b] -> BN+relu -> packed uints, rows padded 496->512 with zeros
    const float4* src = reinterpret_cast<const float4*>(y1 + (size_t)b * (C1 * L1));
    for (int v = tid; v < C1 * 128; v += 384) {
        const int c = v >> 7, i4 = v & 127;
        uint4 o = make_uint4(0, 0, 0, 0);
        if (i4 < 124) {
            const float sc = fin[c], sh = fin[32 + c];
            float4 d = src[c * 124 + i4];
            float e0 = fmaxf(fmaf(d.x, sc, sh), 0.f);
            float e1 = fmaxf(fmaf(d.y, sc, sh), 0.f);
            float e2 = fmaxf(fmaf(d.z, sc, sh), 0.f);
            float e3 = fmaxf(fmaf(d.w, sc, sh), 0.f);
            o = make_uint4(pk(e0), pk(e1), pk(e2), pk(e3));
        }
        *reinterpret_cast<uint4*>(&xs[c][4 * i4]) = o;
    }
    __syncthreads();

    const int lane = tid & 63, wv = tid >> 6;  // 0..5
    const int g = (wv >= 3) ? 1 : 0;
    const int tw = wv - 3 * g;
    const int cl = lane & 31;
    const int kgrp = lane >> 5;
    const int tbase = 5 * (tw * 32 + cl) + kgrp * 8;

    f32x16 hh, hl, lh;
#pragma unroll
    for (int i = 0; i < 16; ++i) { hh[i] = 0.f; hl[i] = 0.f; lh[i] = 0.f; }
    const uint4* wf4 = reinterpret_cast<const uint4*>(wfrag2);

    for (int cc = 0; cc < 16; ++cc) {
        const int c = g * 16 + cc;
        const uint* xc = xs[c];
        const uint4* wfc = wf4 + (size_t)c * 256 + lane;
#pragma unroll
        for (int ks = 0; ks < 2; ++ks) {
            const int idx = tbase + ks * 16;
            uint u0 = xc[idx + 0], u1 = xc[idx + 1], u2 = xc[idx + 2], u3 = xc[idx + 3];
            uint u4 = xc[idx + 4], u5 = xc[idx + 5], u6 = xc[idx + 6], u7 = xc[idx + 7];
            union { s16x8 v; uint u[4]; } ah, al, bh, bl;
            ah.u[0] = __builtin_amdgcn_perm(u1, u0, 0x05040100u);
            al.u[0] = __builtin_amdgcn_perm(u1, u0, 0x07060302u);
            ah.u[1] = __builtin_amdgcn_perm(u3, u2, 0x05040100u);
            al.u[1] = __builtin_amdgcn_perm(u3, u2, 0x07060302u);
            ah.u[2] = __builtin_amdgcn_perm(u5, u4, 0x05040100u);
            al.u[2] = __builtin_amdgcn_perm(u5, u4, 0x07060302u);
            ah.u[3] = __builtin_amdgcn_perm(u7, u6, 0x05040100u);
            al.u[3] = __builtin_amdgcn_perm(u7, u6, 0x07060302u);
            uint4 bq = wfc[ks * 128];
            uint4 lq = wfc[ks * 128 + 64];
            bh.u[0] = bq.x; bh.u[1] = bq.y; bh.u[2] = bq.z; bh.u[3] = bq.w;
            bl.u[0] = lq.x; bl.u[1] = lq.y; bl.u[2] = lq.z; bl.u[3] = lq.w;
            hh = __builtin_amdgcn_mfma_f32_32x32x16_bf16(ah.v, bh.v, hh, 0, 0, 0);
            hl = __builtin_amdgcn_mfma_f32_32x32x16_bf16(ah.v, bl.v, hl, 0, 0, 0);
            lh = __builtin_amdgcn_mfma_f32_32x32x16_bf16(al.v, bh.v, lh, 0, 0, 0);
        }
    }

    f32x16 tot;
#pragma unroll
    for (int i = 0; i < 16; ++i) tot[i] = hh[i] + hl[i] + lh[i];

    __syncthreads();
    float4* pr = reinterpret_cast<float4*>(&xs[0][0]);   // [tile][i4][lane]
    if (g == 1) {
#pragma unroll
        for (int i4 = 0; i4 < 4; ++i4)
            pr[tw * 256 + i4 * 64 + lane] =
                make_float4(tot[4*i4], tot[4*i4+1], tot[4*i4+2], tot[4*i4+3]);
    }
    __syncthreads();

    float sum = 0.f, sq = 0.f;
    if (g == 0) {
        const float bias = c2b[cl];
#pragma unroll
        for (int q = 0; q < 4; ++q) {
            float4 p = pr[tw * 256 + q * 64 + lane];
            float v4[4] = { tot[4*q+0] + p.x + bias, tot[4*q+1] + p.y + bias,
                            tot[4*q+2] + p.z + bias, tot[4*q+3] + p.w + bias };
#pragma unroll
            for (int j = 0; j < 4; ++j) {
                const int t = tw * 32 + 8 * q + 4 * kgrp + j;
                if (t < L2) {
                    y2[((size_t)b * L2 + t) * NF + cl] = v4[j];
                    sum += v4[j]; sq += v4[j] * v4[j];
                }
            }
        }
        sum += __shfl_xor(sum, 32);
        sq  += __shfl_xor(sq, 32);
        if (lane < 32) { redS[tw][cl] = sum; redQ[tw][cl] = sq; }
    }
    __syncthreads();
    if (tid < 64) {
        int o = tid & 31, isQ = tid >> 5;
        float v = isQ ? (redQ[0][o] + redQ[1][o] + redQ[2][o])
                      : (redS[0][o] + redS[1][o] + redS[2][o]);
        atomicAdd(&raw2[(isQ ? 1024 : 0) + o * 16], v);
    }
}

// ---------------- BN2 finalize (inline) + relu, input proj, LN1, fold Wh ----------------
// grid exactly 190 blocks x 256 (= B*T threads). xt2 layout [T][B][HID].
__global__ __launch_bounds__(256) void k_proj(const float* __restrict__ y2,
                                              const float* __restrict__ raw2,
                                              const float* __restrict__ bn2g,
                                              const float* __restrict__ bn2b,
                                              const float* __restrict__ Wi,
                                              const float* __restrict__ bi,
                                              const float* __restrict__ ln1g,
                                              const float* __restrict__ ln1b,
                                              const float* __restrict__ Wh,
                                              const float* __restrict__ bh,
                                              float* __restrict__ xt2) {
    __shared__ float fin[64];
    if (threadIdx.x < 32) {
        const float cnt = 1.f / (float)(B * L2);
        float mean = raw2[threadIdx.x * 16] * cnt;
        float var = raw2[1024 + threadIdx.x * 16] * cnt - mean * mean;
        float sc = bn2g[threadIdx.x] * rsqrtf(var + EPS);
        fin[threadIdx.x] = sc;
        fin[32 + threadIdx.x] = bn2b[threadIdx.x] - mean * sc;
    }
    __syncthreads();

    const int r = blockIdx.x * 256 + threadIdx.x;
    const int b = r / 95, t = r - b * 95;

    const float4* row = reinterpret_cast<const float4*>(y2 + (size_t)r * NF);
    float u[NF];
#pragma unroll
    for (int f4 = 0; f4 < 8; ++f4) {
        float4 v = row[f4];
        u[4*f4]   = fmaxf(fmaf(v.x, fin[4*f4],   fin[32 + 4*f4]),   0.f);
        u[4*f4+1] = fmaxf(fmaf(v.y, fin[4*f4+1], fin[32 + 4*f4+1]), 0.f);
        u[4*f4+2] = fmaxf(fmaf(v.z, fin[4*f4+2], fin[32 + 4*f4+2]), 0.f);
        u[4*f4+3] = fmaxf(fmaf(v.w, fin[4*f4+3], fin[32 + 4*f4+3]), 0.f);
    }
    float xln[LAT];
    float s = 0.f, q = 0.f;
#pragma unroll
    for (int l = 0; l < LAT; ++l) {
        float a = bi[l];
#pragma unroll
        for (int f = 0; f < NF; ++f) a = fmaf(u[f], Wi[l * NF + f], a);
        xln[l] = a; s += a; q += a * a;
    }
    const float m = s * (1.f / LAT);
    const float inv = rsqrtf(q * (1.f / LAT) - m * m + EPS);
#pragma unroll
    for (int l = 0; l < LAT; ++l) xln[l] = (xln[l] - m) * inv * ln1g[l] + ln1b[l];

    float4* dst = reinterpret_cast<float4*>(xt2 + ((size_t)t * B + b) * HID);
#pragma unroll
    for (int j4 = 0; j4 < 16; ++j4) {
        float4 o4;
        float a0 = bh[4*j4], a1 = bh[4*j4+1], a2 = bh[4*j4+2], a3 = bh[4*j4+3];
#pragma unroll
        for (int l = 0; l < LAT; ++l) {
            float xl = xln[l];
            a0 = fmaf(xl, Wh[(4*j4)   * LAT + l], a0);
            a1 = fmaf(xl, Wh[(4*j4+1) * LAT + l], a1);
            a2 = fmaf(xl, Wh[(4*j4+2) * LAT + l], a2);
            a3 = fmaf(xl, Wh[(4*j4+3) * LAT + l], a3);
        }
        o4.x = a0; o4.y = a1; o4.z = a2; o4.w = a3;
        dst[j4] = o4;
    }
}

// ---------------- RNN scan + pooled mean + final linear ----------------
// 1 wave per batch row. LN2 folded into Wr-dot; multi-accumulator dots.
__global__ __launch_bounds__(64) void k_rnn(const float* __restrict__ xt2,
                                            const float* __restrict__ Wh,
                                            const float* __restrict__ ln2g,
                                            const float* __restrict__ ln2b,
                                            const float* __restrict__ Wr,
                                            const float* __restrict__ br,
                                            const float* __restrict__ Wo,
                                            const float* __restrict__ bo,
                                            float* __restrict__ out) {
    __shared__ __align__(16) float aS[64];
    __shared__ __align__(16) float hS[32];
    const int lane = threadIdx.x;
    const int b = blockIdx.x;
    const int l = lane & 31;

    float whv[LAT];
#pragma unroll
    for (int i = 0; i < LAT; ++i) whv[i] = Wh[lane * LAT + i];

    float wg[HID];
    float S1 = 0.f, S2 = br[l];
#pragma unroll
    for (int j = 0; j < HID; ++j) {
        float w = Wr[l * HID + j];
        wg[j] = w * ln2g[j];
        S1 += wg[j];
        S2 = fmaf(w, ln2b[j], S2);
    }

    float hfull[LAT];
#pragma unroll
    for (int i = 0; i < LAT; ++i) hfull[i] = 0.f;
    float pooled = 0.f;
    float xq = xt2[(size_t)b * HID + lane];

    for (int t = 0; t < T; ++t) {
        float xq_next = 0.f;
        if (t + 1 < T) xq_next = xt2[((size_t)(t + 1) * B + b) * HID + lane];

        float a0 = xq, a1 = 0.f, a2c = 0.f, a3c = 0.f;
#pragma unroll
        for (int i = 0; i < 8; ++i) {
            a0  = fmaf(hfull[4*i+0], whv[4*i+0], a0);
            a1  = fmaf(hfull[4*i+1], whv[4*i+1], a1);
            a2c = fmaf(hfull[4*i+2], whv[4*i+2], a2c);
            a3c = fmaf(hfull[4*i+3], whv[4*i+3], a3c);
        }
        const float a = fmaxf((a0 + a1) + (a2c + a3c), 0.f);

        aS[lane] = a;
        asm volatile("s_waitcnt lgkmcnt(0)" ::: "memory");

        float d0 = 0.f, d1 = 0.f, d2 = 0.f, d3 = 0.f;
#pragma unroll
        for (int i = 0; i < 16; ++i) {
            float4 v = reinterpret_cast<const float4*>(aS)[i];
            d0 = fmaf(v.x, wg[4*i+0], d0); d1 = fmaf(v.y, wg[4*i+1], d1);
            d2 = fmaf(v.z, wg[4*i+2], d2); d3 = fmaf(v.w, wg[4*i+3], d3);
        }
        float s = a, q = a * a;
#pragma unroll
        for (int off = 32; off >= 1; off >>= 1) { s += __shfl_xor(s, off); q += __shfl_xor(q, off); }
        const float m = s * (1.f / HID);
        const float inv = __builtin_amdgcn_rsqf(q * (1.f / HID) - m * m + EPS);
        const float dot = (d0 + d1) + (d2 + d3);
        const float a2v = fmaf(inv, dot - m * S1, S2);

        const float z = __builtin_amdgcn_exp2f(2.8853900817779268f * a2v);
        const float h = 1.f - 2.f * __builtin_amdgcn_rcpf(z + 1.f);
        pooled += h;

        if (lane < 32) hS[lane] = h;
        asm volatile("s_waitcnt lgkmcnt(0)" ::: "memory");
#pragma unroll
        for (int i = 0; i < 8; ++i) {
            float4 hv = reinterpret_cast<const float4*>(hS)[i];
            hfull[4*i] = hv.x; hfull[4*i+1] = hv.y; hfull[4*i+2] = hv.z; hfull[4*i+3] = hv.w;
        }
        xq = xq_next;
    }
    pooled *= (1.f / T);
    if (lane < 32) aS[lane] = pooled;
    asm volatile("s_waitcnt lgkmcnt(0)" ::: "memory");

    float wov[LAT];
#pragma unroll
    for (int i = 0; i < LAT; ++i) wov[i] = Wo[l * LAT + i];
    float b0 = bo[l], b1 = 0.f, b2 = 0.f, b3 = 0.f;
#pragma unroll
    for (int i = 0; i < 8; ++i) {
        float4 pv = reinterpret_cast<const float4*>(aS)[i];
        b0 = fmaf(pv.x, wov[4*i+0], b0); b1 = fmaf(pv.y, wov[4*i+1], b1);
        b2 = fmaf(pv.z, wov[4*i+2], b2); b3 = fmaf(pv.w, wov[4*i+3], b3);
    }
    if (lane < 32) out[(size_t)b * LAT + l] = (b0 + b1) + (b2 + b3);
}

extern "C" void kernel_launch(void* const* d_in, const int* in_sizes, int n_in,
                              void* d_out, int out_size, void* d_ws, size_t ws_size,
                              hipStream_t stream) {
    const float* x    = (const float*)d_in[0];
    const float* c1w  = (const float*)d_in[1];
    const float* c1b  = (const float*)d_in[2];
    const float* bn1g = (const float*)d_in[3];
    const float* bn1b = (const float*)d_in[4];
    const float* c2w  = (const float*)d_in[5];
    const float* c2b  = (const float*)d_in[6];
    const float* bn2g = (const float*)d_in[7];
    const float* bn2b = (const float*)d_in[8];
    const float* Wi   = (const float*)d_in[9];
    const float* bi   = (const float*)d_in[10];
    const float* ln1g = (const float*)d_in[11];
    const float* ln1b = (const float*)d_in[12];
    const float* Wh   = (const float*)d_in[13];
    const float* bh   = (const float*)d_in[14];
    const float* ln2g = (const float*)d_in[15];
    const float* ln2b = (const float*)d_in[16];
    const float* Wr   = (const float*)d_in[17];
    const float* br   = (const float*)d_in[18];
    const float* Wo   = (const float*)d_in[19];
    const float* bo   = (const float*)d_in[20];

    float* ws = (float*)d_ws;
    float* raw1 = ws;                      // 2048 (S at o*16, Q at 1024+o*16)
    float* raw2 = ws + 2048;               // 2048
    ushort* wfrag1 = (ushort*)(ws + 4096); // 49152 ushorts -> ends 28672
    ushort* wfrag2 = (ushort*)(ws + 28672);// 65536 ushorts -> ends 61440
    float* y1   = ws + 61440;              // 8126464 -> ends 8187904
    float* y2   = ws + 8187904;            // 1556480 -> ends 9744384
    float* xt2  = y1;                      // alias y1 (dead after conv2)
    float* out  = (float*)d_out;

    hipMemsetAsync(raw1, 0, 4096 * sizeof(float), stream);
    k_prep_w<<<56, 256, 0, stream>>>(c1w, c2w, wfrag1, wfrag2);
    k_conv1<<<dim3(4, B), 512, 0, stream>>>(x, wfrag1, c1b, y1, raw1);
    k_conv2<<<B, 384, 0, stream>>>(y1, wfrag2, c2b, raw1, bn1g, bn1b, y2, raw2);
    k_proj<<<190, 256, 0, stream>>>(y2, raw2, bn2g, bn2b, Wi, bi, ln1g, ln1b, Wh, bh, xt2);
    k_rnn<<<B, 64, 0, stream>>>(xt2, Wh, ln2g, ln2b, Wr, br, Wo, bo, out);
}